// Round 3
// baseline (15374.039 us; speedup 1.0000x reference)
//
#include <hip/hip_runtime.h>
#include <math.h>

#define HID 512
#define TENC 16384
#define NBLK 256
#define TPB 1024
#define NGRP 32
#define GRPSZ 8
#define VOCAB 31
#define EOSI 29
#define MAXLEN 100
#define SCALE 0.044194173824159216f

// ws layout (4-byte units)
#define WS_GX    0          // 31*1536
#define WS_GH    47616      // 1536
#define WS_SUMRY 49152      // 512
#define WS_M     49664      // 256
#define WS_S     49920      // 256
#define WS_U     50176      // 256*512
#define WS_BAR   181248     // 200 instances * 32 counters * 4-int pad = 25600 ints

// d_out layout: [0..3099] logits, [3100] length (float), [3101..] attn (100*16384)
#define OUT_LEN_IDX 3100
#define OUT_ATT_BASE 3101

static __device__ __forceinline__ float wsum(float v) {
#pragma unroll
  for (int m = 32; m >= 1; m >>= 1) v += __shfl_xor(v, m, 64);
  return v;
}
static __device__ __forceinline__ float sigm(float x) { return 1.0f / (1.0f + expf(-x)); }

__global__ __launch_bounds__(1024) void k_init(const float* __restrict__ b_hh,
                                               float* __restrict__ ws) {
  int idx = blockIdx.x * 1024 + threadIdx.x;
  int* bars = (int*)ws + WS_BAR;
  if (idx < 25600) bars[idx] = 0;
  if (idx < 1536) ws[WS_GH + idx] = b_hh[idx];  // gh(0) = W_hh*0 + b_hh
}

// GX_all[v][r] = w_ih[r,:]·embed[v,:] + b_ih[r]
__global__ __launch_bounds__(256) void k_gx_all(const float* __restrict__ embed,
                                                const float* __restrict__ w_ih,
                                                const float* __restrict__ b_ih,
                                                float* __restrict__ ws) {
  int w = threadIdx.x >> 6, lane = threadIdx.x & 63;
  int r = blockIdx.x * 4 + w;
  float wr[8];
  const float* wp = w_ih + (size_t)r * HID + lane * 8;
#pragma unroll
  for (int j = 0; j < 8; ++j) wr[j] = wp[j];
  float b = b_ih[r];
  for (int v = 0; v < VOCAB; ++v) {
    const float* e = embed + (size_t)v * HID + lane * 8;
    float d = 0.f;
#pragma unroll
    for (int j = 0; j < 8; ++j) d += wr[j] * e[j];
    d = wsum(d);
    if (lane == 0) ws[WS_GX + v * 1536 + r] = d + b;
  }
}

// two-level grid barrier: 32 padded counters (same-XCD groups of 8 under %8 round-robin)
static __device__ __forceinline__ void gridbar(int* base) {
  __syncthreads();  // drains all waves' stores to L2 (compiler emits vmcnt(0) before s_barrier)
  if (threadIdx.x == 0)
    __hip_atomic_fetch_add(base + (blockIdx.x & (NGRP - 1)) * 4, 1,
                           __ATOMIC_RELEASE, __HIP_MEMORY_SCOPE_AGENT);
  if (threadIdx.x < NGRP) {
    while (__hip_atomic_load(base + threadIdx.x * 4,
                             __ATOMIC_RELAXED, __HIP_MEMORY_SCOPE_AGENT) < GRPSZ)
      __builtin_amdgcn_s_sleep(2);
  }
  __syncthreads();
  __threadfence();  // acquire: invalidate so subsequent reads see remote data
}

__global__ __launch_bounds__(TPB) void k_persist(const float* __restrict__ enc,
                                                 const float* __restrict__ w_hh,
                                                 const float* __restrict__ b_hh,
                                                 const float* __restrict__ w_out,
                                                 const float* __restrict__ b_out,
                                                 float* __restrict__ ws,
                                                 float* __restrict__ dout) {
  const int tid = threadIdx.x, blk = blockIdx.x;
  const int w = tid >> 6, lane = tid & 63;
  __shared__ __align__(16) float h2[2][HID];
  __shared__ __align__(16) float uld[HID];
  __shared__ float sblk[64];
  __shared__ float redMS[8];
  __shared__ float redU[8];
  __shared__ float lgs[32];
  __shared__ float bMS;
  int best = EOSI, len = MAXLEN;
  int* bars = (int*)ws + WS_BAR;

  if (tid < HID) h2[0][tid] = 0.f;  // h(0) = 0 (sync before first use below)

#pragma unroll 1
  for (int t = 0; ; ++t) {
    float* h  = h2[t & 1];        // h(t) = h_new(t-1)
    float* hn = h2[(t + 1) & 1];  // will hold h(t+1)

    // ---------- logits(t-1) + argmax -> best (redundant per block) ----------
    if (t > 0) {
#pragma unroll
      for (int rr = 0; rr < 2; ++rr) {
        int r = w + rr * 16;
        if (r < VOCAB) {
          const float* wo = w_out + (size_t)r * 1024;
          const float* sm = ws + WS_SUMRY;
          float4 a0 = *(const float4*)(wo + lane * 4);
          float4 a1 = *(const float4*)(wo + 256 + lane * 4);
          float4 b0 = *(const float4*)(wo + 512 + lane * 4);
          float4 b1 = *(const float4*)(wo + 768 + lane * 4);
          float4 x0 = *(const float4*)(sm + lane * 4);
          float4 x1 = *(const float4*)(sm + 256 + lane * 4);
          float4 y0 = *(const float4*)(&h[lane * 4]);
          float4 y1 = *(const float4*)(&h[256 + lane * 4]);
          float acc = a0.x*x0.x + a0.y*x0.y + a0.z*x0.z + a0.w*x0.w
                    + a1.x*x1.x + a1.y*x1.y + a1.z*x1.z + a1.w*x1.w
                    + b0.x*y0.x + b0.y*y0.y + b0.z*y0.z + b0.w*y0.w
                    + b1.x*y1.x + b1.y*y1.y + b1.z*y1.z + b1.w*y1.w;
          acc = wsum(acc);
          if (lane == 0) lgs[r] = acc + b_out[r];
        }
      }
      __syncthreads();
      float bv = lgs[0];
      int bb = 0;
#pragma unroll
      for (int v = 1; v < VOCAB; ++v) {
        float x = lgs[v];
        if (x > bv) { bv = x; bb = v; }
      }
      best = bb;
      if (bb == EOSI && len == MAXLEN) len = t - 1;
      if (blk == 0) {
        if (tid < VOCAB) dout[(size_t)(t - 1) * VOCAB + tid] = lgs[tid];
        if (t == MAXLEN && tid == 0) dout[OUT_LEN_IDX] = (float)len;
      }
    }
    if (t == MAXLEN) break;

    // ---------- GRU h_new (redundant per block, bitwise identical) ----------
    {
      const float* gx = ws + WS_GX + best * 1536;
      const float* gh = ws + WS_GH;
      if (tid < HID) {
        float rg = sigm(gx[tid] + gh[tid]);
        float zg = sigm(gx[HID + tid] + gh[HID + tid]);
        float ng = tanhf(gx[2 * HID + tid] + rg * gh[2 * HID + tid]);
        hn[tid] = (1.f - zg) * ng + zg * h[tid];
        uld[tid] = 0.f;
      }
    }
    __syncthreads();

    // ---------- scores + PV partials (64 keys per block) ----------
    float hr[8];
#pragma unroll
    for (int j = 0; j < 8; ++j) hr[j] = hn[lane * 8 + j];
    float4 vv[4][2];
    float sc[4];
#pragma unroll
    for (int rr = 0; rr < 4; ++rr) {
      int trow = blk * 64 + w * 4 + rr;
      const float* rowp = enc + (size_t)trow * 1024 + lane * 8;
      float4 k0 = *(const float4*)(rowp);
      float4 k1 = *(const float4*)(rowp + 4);
      vv[rr][0] = *(const float4*)(rowp + 512);
      vv[rr][1] = *(const float4*)(rowp + 516);
      float d = hr[0]*k0.x + hr[1]*k0.y + hr[2]*k0.z + hr[3]*k0.w
              + hr[4]*k1.x + hr[5]*k1.y + hr[6]*k1.z + hr[7]*k1.w;
      bool okl = (k0.x != 30.f) || (k0.y != 30.f) || (k0.z != 30.f) || (k0.w != 30.f)
               || (k1.x != 30.f) || (k1.y != 30.f) || (k1.z != 30.f) || (k1.w != 30.f);
      float s = wsum(d);
      bool ok = (__ballot(okl) != 0ull);
      sc[rr] = ok ? s * SCALE : -1000000000.0f;
      if (lane == 0) sblk[w * 4 + rr] = sc[rr];
    }
    __syncthreads();
    if (tid < 64) {
      float m = sblk[tid];
#pragma unroll
      for (int msk = 32; msk >= 1; msk >>= 1) m = fmaxf(m, __shfl_xor(m, msk, 64));
      if (tid == 0) bMS = m;
    }
    __syncthreads();
    float m_b = bMS;
    {
      float ps[8] = {0, 0, 0, 0, 0, 0, 0, 0};
#pragma unroll
      for (int rr = 0; rr < 4; ++rr) {
        float a = expf(sc[rr] - m_b);
        float4 v0 = vv[rr][0], v1 = vv[rr][1];
        ps[0] += a * v0.x; ps[1] += a * v0.y; ps[2] += a * v0.z; ps[3] += a * v0.w;
        ps[4] += a * v1.x; ps[5] += a * v1.y; ps[6] += a * v1.z; ps[7] += a * v1.w;
      }
#pragma unroll
      for (int j = 0; j < 8; ++j) atomicAdd(&uld[lane * 8 + j], ps[j]);
    }
    if (tid < 64) {
      float e = expf(sblk[tid] - m_b);
      e = wsum(e);
      if (tid == 0) { ws[WS_M + blk] = m_b; ws[WS_S + blk] = e; }
    }
    __syncthreads();
    if (tid < HID) ws[WS_U + (size_t)blk * HID + tid] = uld[tid];
    gridbar(bars + (size_t)(t * 2 + 0) * (NGRP * 4));

    // ---------- phase C: gh(t+1); global M,S; attn; summary dims ----------
    if (w >= 8 && w < 14) {  // gh rows blk*6 .. blk*6+5, from LDS hn
      int r = blk * 6 + (w - 8);
      const float* wp = w_hh + (size_t)r * HID + lane * 8;
      float4 w0 = *(const float4*)(wp);
      float4 w1 = *(const float4*)(wp + 4);
      float4 hv0 = *(const float4*)(&hn[lane * 8]);
      float4 hv1 = *(const float4*)(&hn[lane * 8 + 4]);
      float acc = w0.x*hv0.x + w0.y*hv0.y + w0.z*hv0.z + w0.w*hv0.w
                + w1.x*hv1.x + w1.y*hv1.y + w1.z*hv1.z + w1.w*hv1.w;
      acc = wsum(acc);
      if (lane == 0) ws[WS_GH + r] = acc + b_hh[r];
    }
    if (tid < 256) {  // waves 0-3: combine 256 (m,s) partials
      float m = ws[WS_M + tid], s = ws[WS_S + tid];
#pragma unroll
      for (int msk = 32; msk >= 1; msk >>= 1) {
        float m2 = __shfl_xor(m, msk, 64), s2 = __shfl_xor(s, msk, 64);
        float Mn = fmaxf(m, m2);
        s = s * expf(m - Mn) + s2 * expf(m2 - Mn);
        m = Mn;
      }
      if (lane == 0) { redMS[w * 2] = m; redMS[w * 2 + 1] = s; }
    }
    __syncthreads();
    float M = redMS[0], S = redMS[1];
#pragma unroll
    for (int k = 1; k < 4; ++k) {
      float m2 = redMS[k * 2], s2 = redMS[k * 2 + 1];
      float Mn = fmaxf(M, m2);
      S = S * expf(M - Mn) + s2 * expf(m2 - Mn);
      M = Mn;
    }
    float invS = 1.0f / S;
    if (tid < 64) {
      float a = expf(sblk[tid] - M) * invS;
      dout[OUT_ATT_BASE + (size_t)t * TENC + blk * 64 + tid] = a;
    }
    if (tid < 512) {  // summary dims d0=blk*2 (+ tid>>8): reduce over 256 U partials
      int b = tid & 255, dloc = tid >> 8;
      float e = expf(ws[WS_M + b] - M);
      float vsum = e * ws[WS_U + (size_t)b * HID + blk * 2 + dloc];
      vsum = wsum(vsum);
      if (lane == 0) redU[w] = vsum;
    }
    __syncthreads();
    if (tid == 0) {
      ws[WS_SUMRY + blk * 2]     = (redU[0] + redU[1] + redU[2] + redU[3]) * invS;
      ws[WS_SUMRY + blk * 2 + 1] = (redU[4] + redU[5] + redU[6] + redU[7]) * invS;
    }
    gridbar(bars + (size_t)(t * 2 + 1) * (NGRP * 4));
  }
}

extern "C" void kernel_launch(void* const* d_in, const int* in_sizes, int n_in,
                              void* d_out, int out_size, void* d_ws, size_t ws_size,
                              hipStream_t stream) {
  const float* enc   = (const float*)d_in[0];
  const float* embed = (const float*)d_in[2];
  const float* w_ih  = (const float*)d_in[3];
  const float* w_hh  = (const float*)d_in[4];
  const float* b_ih  = (const float*)d_in[5];
  const float* b_hh  = (const float*)d_in[6];
  const float* w_out = (const float*)d_in[7];
  const float* b_out = (const float*)d_in[8];
  float* dout = (float*)d_out;
  float* ws = (float*)d_ws;

  hipLaunchKernelGGL(k_init, dim3(26), dim3(1024), 0, stream, b_hh, ws);
  hipLaunchKernelGGL(k_gx_all, dim3(384), dim3(256), 0, stream, embed, w_ih, b_ih, ws);
  hipLaunchKernelGGL(k_persist, dim3(NBLK), dim3(TPB), 0, stream,
                     enc, w_hh, b_hh, w_out, b_out, ws, dout);
}

// Round 5
// 6434.300 us; speedup vs baseline: 2.3894x; 2.3894x over previous
//
#include <hip/hip_runtime.h>
#include <math.h>

#define HID 512
#define TENC 16384
#define NBLK 64
#define TPB 1024
#define KPB 256          // keys per block
#define NGRP 8
#define GRPSZ 8
#define VOCAB 31
#define EOSI 29
#define MAXLEN 100
#define SCALE 0.044194173824159216f

// ws layout (4-byte units)
#define WS_GX    0          // 31*1536
#define WS_GH    47616      // 2*1536 (double buffer)
#define WS_M     50688      // 2*64
#define WS_S     50816      // 2*64
#define WS_U     50944      // 2*64*512
#define WS_BAR   116480     // ints: 100 inst * 8 grp * 16 pad = 12800, epoch at +12800

#define OUT_LEN_IDX 3100
#define OUT_ATT_BASE 3101

static __device__ __forceinline__ float wsum(float v) {
#pragma unroll
  for (int m = 32; m >= 1; m >>= 1) v += __shfl_xor(v, m, 64);
  return v;
}
static __device__ __forceinline__ float sigm(float x) { return 1.0f / (1.0f + expf(-x)); }

__global__ __launch_bounds__(1024) void k_init(const float* __restrict__ b_hh,
                                               float* __restrict__ ws) {
  int idx = blockIdx.x * 1024 + threadIdx.x;
  int* bars = (int*)ws + WS_BAR;
  if (idx < 12816) bars[idx] = 0;
  if (idx < 1536) ws[WS_GH + idx] = b_hh[idx];  // gh(0) = W_hh*0 + b_hh -> buf 0
}

__global__ __launch_bounds__(256) void k_gx_all(const float* __restrict__ embed,
                                                const float* __restrict__ w_ih,
                                                const float* __restrict__ b_ih,
                                                float* __restrict__ ws) {
  int w = threadIdx.x >> 6, lane = threadIdx.x & 63;
  int r = blockIdx.x * 4 + w;
  float wr[8];
  const float* wp = w_ih + (size_t)r * HID + lane * 8;
#pragma unroll
  for (int j = 0; j < 8; ++j) wr[j] = wp[j];
  float b = b_ih[r];
  for (int v = 0; v < VOCAB; ++v) {
    const float* e = embed + (size_t)v * HID + lane * 8;
    float d = 0.f;
#pragma unroll
    for (int j = 0; j < 8; ++j) d += wr[j] * e[j];
    d = wsum(d);
    if (lane == 0) ws[WS_GX + v * 1536 + r] = d + b;
  }
}

// grid barrier: 8 XCD-grouped counters, master block 0 publishes monotonic epoch
static __device__ __forceinline__ void gridbar(int* bars, int t) {
  __syncthreads();
  int* cnt = bars + t * (NGRP * 16);
  int* epoch = bars + MAXLEN * (NGRP * 16);
  if (threadIdx.x == 0) {
    __threadfence();
    __hip_atomic_fetch_add(cnt + (blockIdx.x & (NGRP - 1)) * 16, 1,
                           __ATOMIC_RELEASE, __HIP_MEMORY_SCOPE_AGENT);
    if (blockIdx.x == 0) {
#pragma unroll 1
      for (int g = 0; g < NGRP; ++g) {
        while (__hip_atomic_load(cnt + g * 16, __ATOMIC_ACQUIRE,
                                 __HIP_MEMORY_SCOPE_AGENT) < GRPSZ)
          __builtin_amdgcn_s_sleep(2);
      }
      __hip_atomic_store(epoch, t + 1, __ATOMIC_RELEASE, __HIP_MEMORY_SCOPE_AGENT);
    } else {
      while (__hip_atomic_load(epoch, __ATOMIC_ACQUIRE,
                               __HIP_MEMORY_SCOPE_AGENT) < t + 1)
        __builtin_amdgcn_s_sleep(2);
    }
    __threadfence();
  }
  __syncthreads();
}

__global__ __launch_bounds__(TPB) void k_persist(const float* __restrict__ enc,
                                                 const float* __restrict__ w_hh,
                                                 const float* __restrict__ b_hh,
                                                 const float* __restrict__ w_out,
                                                 const float* __restrict__ b_out,
                                                 float* __restrict__ ws,
                                                 float* __restrict__ dout) {
  const int tid = threadIdx.x, blk = blockIdx.x;
  const int w = tid >> 6, lane = tid & 63;
  __shared__ __align__(16) float h2[2][HID];
  __shared__ __align__(16) float uld[HID];
  __shared__ __align__(16) float smry[HID];
  __shared__ float sblk[KPB];
  __shared__ float eb[64];
  __shared__ float lgs[32];
  __shared__ float redA[16];
  __shared__ float redB[4];
  int best = EOSI, len = MAXLEN;
  int* bars = (int*)ws + WS_BAR;

  if (tid < HID) h2[0][tid] = 0.f;
  __syncthreads();

#pragma unroll 1
  for (int t = 0;; ++t) {
    float* h = h2[t & 1];          // h(t)
    float* hnw = h2[(t + 1) & 1];  // h(t+1)

    // ============ reduce partials(t-1); attn(t-1); logits(t-1); best ============
    if (t > 0) {
      const float* Mp = ws + WS_M + ((t + 1) & 1) * 64;
      const float* Sp = ws + WS_S + ((t + 1) & 1) * 64;
      const float* Up = ws + WS_U + ((t + 1) & 1) * (64 * HID);
      if (tid < 64) {
        float m = Mp[tid], s = Sp[tid];
#pragma unroll
        for (int msk = 32; msk >= 1; msk >>= 1) {
          float m2 = __shfl_xor(m, msk, 64), s2 = __shfl_xor(s, msk, 64);
          float Mn = fmaxf(m, m2);
          s = s * expf(m - Mn) + s2 * expf(m2 - Mn);
          m = Mn;
        }
        if (lane == 0) { redB[0] = m; redB[1] = s; }
      }
      __syncthreads();
      float M = redB[0], invS = 1.0f / redB[1];
      if (tid < 64) eb[tid] = expf(Mp[tid] - M);
      if (tid < KPB) {  // attn(t-1): own scores still in LDS
        float a = expf(sblk[tid] - M) * invS;
        dout[OUT_ATT_BASE + (size_t)(t - 1) * TENC + blk * KPB + tid] = a;
      }
      __syncthreads();
      if (tid < HID) {  // summary (redundant, coalesced over 64 partials)
        float acc = 0.f;
#pragma unroll 8
        for (int b = 0; b < 64; ++b) acc += eb[b] * Up[b * HID + tid];
        smry[tid] = acc * invS;
      }
      __syncthreads();
      // logits (redundant)
#pragma unroll
      for (int rr = 0; rr < 2; ++rr) {
        int r = w + rr * 16;
        if (r < VOCAB) {
          const float* wo = w_out + (size_t)r * 1024;
          float4 a0 = *(const float4*)(wo + lane * 4);
          float4 a1 = *(const float4*)(wo + 256 + lane * 4);
          float4 b0 = *(const float4*)(wo + 512 + lane * 4);
          float4 b1 = *(const float4*)(wo + 768 + lane * 4);
          float4 x0 = *(const float4*)(&smry[lane * 4]);
          float4 x1 = *(const float4*)(&smry[256 + lane * 4]);
          float4 y0 = *(const float4*)(&h[lane * 4]);
          float4 y1 = *(const float4*)(&h[256 + lane * 4]);
          float acc = a0.x*x0.x + a0.y*x0.y + a0.z*x0.z + a0.w*x0.w
                    + a1.x*x1.x + a1.y*x1.y + a1.z*x1.z + a1.w*x1.w
                    + b0.x*y0.x + b0.y*y0.y + b0.z*y0.z + b0.w*y0.w
                    + b1.x*y1.x + b1.y*y1.y + b1.z*y1.z + b1.w*y1.w;
          acc = wsum(acc);
          if (lane == 0) lgs[r] = acc + b_out[r];
        }
      }
      __syncthreads();
      float bv = lgs[0];
      int bb = 0;
#pragma unroll
      for (int v = 1; v < VOCAB; ++v) {
        float x = lgs[v];
        if (x > bv) { bv = x; bb = v; }
      }
      best = bb;
      if (bb == EOSI && len == MAXLEN) len = t - 1;
      if (blk == 0) {
        if (tid < VOCAB) dout[(size_t)(t - 1) * VOCAB + tid] = lgs[tid];
        if (t == MAXLEN && tid == 0) dout[OUT_LEN_IDX] = (float)len;
      }
    }
    if (t == MAXLEN) break;

    // ============ GRU h(t+1) (redundant) ============
    {
      const float* gx = ws + WS_GX + best * 1536;
      const float* gh = ws + WS_GH + (t & 1) * 1536;
      if (tid < HID) {
        float rg = sigm(gx[tid] + gh[tid]);
        float zg = sigm(gx[HID + tid] + gh[HID + tid]);
        float ng = tanhf(gx[2 * HID + tid] + rg * gh[2 * HID + tid]);
        hnw[tid] = (1.f - zg) * ng + zg * h[tid];
        uld[tid] = 0.f;
      }
    }
    __syncthreads();

    // ============ gh(t+1) slice: rows blk*24 .. +23 ============
    {
      float* ghw = ws + WS_GH + ((t + 1) & 1) * 1536;
      float4 hv0 = *(const float4*)(&hnw[lane * 8]);
      float4 hv1 = *(const float4*)(&hnw[lane * 8 + 4]);
      int r = blk * 24 + w;
      const float* wp = w_hh + (size_t)r * HID + lane * 8;
      float4 w0 = *(const float4*)(wp);
      float4 w1 = *(const float4*)(wp + 4);
      float acc = w0.x*hv0.x + w0.y*hv0.y + w0.z*hv0.z + w0.w*hv0.w
                + w1.x*hv1.x + w1.y*hv1.y + w1.z*hv1.z + w1.w*hv1.w;
      acc = wsum(acc);
      if (lane == 0) ghw[r] = acc + b_hh[r];
      if (w < 8) {
        int r2 = blk * 24 + 16 + w;
        const float* wp2 = w_hh + (size_t)r2 * HID + lane * 8;
        float4 u0 = *(const float4*)(wp2);
        float4 u1 = *(const float4*)(wp2 + 4);
        float acc2 = u0.x*hv0.x + u0.y*hv0.y + u0.z*hv0.z + u0.w*hv0.w
                   + u1.x*hv1.x + u1.y*hv1.y + u1.z*hv1.z + u1.w*hv1.w;
        acc2 = wsum(acc2);
        if (lane == 0) ghw[r2] = acc2 + b_hh[r2];
      }
    }

    // ============ scores: 256 keys, wave w -> rows w*16..w*16+15 ============
    float hr[8];
#pragma unroll
    for (int j = 0; j < 8; ++j) hr[j] = hnw[lane * 8 + j];
    float sc[16];
#pragma unroll
    for (int b4 = 0; b4 < 4; ++b4) {
      float4 k0[4], k1[4];
#pragma unroll
      for (int j = 0; j < 4; ++j) {
        int trow = blk * KPB + w * 16 + b4 * 4 + j;
        const float* rowp = enc + (size_t)trow * 1024 + lane * 8;
        k0[j] = *(const float4*)(rowp);
        k1[j] = *(const float4*)(rowp + 4);
      }
#pragma unroll
      for (int j = 0; j < 4; ++j) {
        float d = hr[0]*k0[j].x + hr[1]*k0[j].y + hr[2]*k0[j].z + hr[3]*k0[j].w
                + hr[4]*k1[j].x + hr[5]*k1[j].y + hr[6]*k1[j].z + hr[7]*k1[j].w;
        bool okl = (k0[j].x != 30.f) || (k0[j].y != 30.f) || (k0[j].z != 30.f) || (k0[j].w != 30.f)
                 || (k1[j].x != 30.f) || (k1[j].y != 30.f) || (k1[j].z != 30.f) || (k1[j].w != 30.f);
        float s = wsum(d);
        bool ok = (__ballot(okl) != 0ull);
        sc[b4 * 4 + j] = ok ? s * SCALE : -1000000000.0f;
        if (lane == 0) sblk[w * 16 + b4 * 4 + j] = sc[b4 * 4 + j];
      }
    }
    __syncthreads();
    // block max
    if (tid < KPB) {
      float m = sblk[tid];
#pragma unroll
      for (int msk = 32; msk >= 1; msk >>= 1) m = fmaxf(m, __shfl_xor(m, msk, 64));
      if (lane == 0) redA[w] = m;
    }
    __syncthreads();
    if (tid == 0) redA[4] = fmaxf(fmaxf(redA[0], redA[1]), fmaxf(redA[2], redA[3]));
    __syncthreads();
    float Mb = redA[4];
    // block expsum
    if (tid < KPB) {
      float e = expf(sblk[tid] - Mb);
      e = wsum(e);
      if (lane == 0) redA[8 + w] = e;
    }
    // PV partials
    {
      float ps[8] = {0, 0, 0, 0, 0, 0, 0, 0};
#pragma unroll
      for (int b4 = 0; b4 < 4; ++b4) {
        float4 v0[4], v1[4];
#pragma unroll
        for (int j = 0; j < 4; ++j) {
          int trow = blk * KPB + w * 16 + b4 * 4 + j;
          const float* rowp = enc + (size_t)trow * 1024 + 512 + lane * 8;
          v0[j] = *(const float4*)(rowp);
          v1[j] = *(const float4*)(rowp + 4);
        }
#pragma unroll
        for (int j = 0; j < 4; ++j) {
          float a = expf(sc[b4 * 4 + j] - Mb);
          ps[0] += a * v0[j].x; ps[1] += a * v0[j].y; ps[2] += a * v0[j].z; ps[3] += a * v0[j].w;
          ps[4] += a * v1[j].x; ps[5] += a * v1[j].y; ps[6] += a * v1[j].z; ps[7] += a * v1[j].w;
        }
      }
#pragma unroll
      for (int j = 0; j < 8; ++j) atomicAdd(&uld[lane * 8 + j], ps[j]);
    }
    __syncthreads();
    if (tid == 0) {
      ws[WS_M + (t & 1) * 64 + blk] = Mb;
      ws[WS_S + (t & 1) * 64 + blk] = redA[8] + redA[9] + redA[10] + redA[11];
    }
    if (tid < HID) ws[WS_U + (t & 1) * (64 * HID) + (size_t)blk * HID + tid] = uld[tid];

    gridbar(bars, t);
  }
}

extern "C" void kernel_launch(void* const* d_in, const int* in_sizes, int n_in,
                              void* d_out, int out_size, void* d_ws, size_t ws_size,
                              hipStream_t stream) {
  const float* enc   = (const float*)d_in[0];
  const float* embed = (const float*)d_in[2];
  const float* w_ih  = (const float*)d_in[3];
  const float* w_hh  = (const float*)d_in[4];
  const float* b_ih  = (const float*)d_in[5];
  const float* b_hh  = (const float*)d_in[6];
  const float* w_out = (const float*)d_in[7];
  const float* b_out = (const float*)d_in[8];
  float* dout = (float*)d_out;
  float* ws = (float*)d_ws;

  hipLaunchKernelGGL(k_init, dim3(13), dim3(1024), 0, stream, b_hh, ws);
  hipLaunchKernelGGL(k_gx_all, dim3(384), dim3(256), 0, stream, embed, w_ih, b_ih, ws);
  hipLaunchKernelGGL(k_persist, dim3(NBLK), dim3(TPB), 0, stream,
                     enc, w_hh, b_hh, w_out, b_out, ws, dout);
}

// Round 6
// 3546.043 us; speedup vs baseline: 4.3355x; 1.8145x over previous
//
#include <hip/hip_runtime.h>
#include <math.h>

#define HID 512
#define TENC 16384
#define NBLK 256
#define TPB 512
#define KPB 64
#define NGRP 32
#define GRPSZ 8
#define VOCAB 31
#define EOSI 29
#define MAXLEN 100
#define SCALE 0.044194173824159216f

// ws layout (4-byte units)
#define WS_GX    0          // 31*1536 = 47616
#define WS_GH    47616      // 2*1536 (double buffer)
#define WS_LT    50688      // 3 buffers * 272  (8 slots*32 lognum, +256: 8 T1)
#define WS_BAR   51504      // ints: 100*128 counters + 8*4 epoch = 12832

#define OUT_LEN_IDX 3100
#define OUT_ATT_BASE 3101

#define AL(p)    __hip_atomic_load((p), __ATOMIC_RELAXED, __HIP_MEMORY_SCOPE_AGENT)
#define AS(p, v) __hip_atomic_store((p), (v), __ATOMIC_RELAXED, __HIP_MEMORY_SCOPE_AGENT)

static __device__ __forceinline__ float wsum(float v) {
#pragma unroll
  for (int m = 32; m >= 1; m >>= 1) v += __shfl_xor(v, m, 64);
  return v;
}
static __device__ __forceinline__ float sigm(float x) { return 1.0f / (1.0f + expf(-x)); }

__global__ __launch_bounds__(1024) void k_init(const float* __restrict__ b_hh,
                                               float* __restrict__ ws) {
  int idx = blockIdx.x * 1024 + threadIdx.x;
  int* bars = (int*)ws + WS_BAR;
  if (idx < 12832) bars[idx] = 0;
  if (idx < 1536) ws[WS_GH + idx] = b_hh[idx];  // gh(0) = W_hh*0 + b_hh (buffer 0)
  if (idx < 816) ws[WS_LT + idx] = 0.0f;        // all 3 LT buffers
}

__global__ __launch_bounds__(256) void k_gx_all(const float* __restrict__ embed,
                                                const float* __restrict__ w_ih,
                                                const float* __restrict__ b_ih,
                                                float* __restrict__ ws) {
  int w = threadIdx.x >> 6, lane = threadIdx.x & 63;
  int r = blockIdx.x * 4 + w;
  float wr[8];
  const float* wp = w_ih + (size_t)r * HID + lane * 8;
#pragma unroll
  for (int j = 0; j < 8; ++j) wr[j] = wp[j];
  float b = b_ih[r];
  for (int v = 0; v < VOCAB; ++v) {
    const float* e = embed + (size_t)v * HID + lane * 8;
    float d = 0.f;
#pragma unroll
    for (int j = 0; j < 8; ++j) d += wr[j] * e[j];
    d = wsum(d);
    if (lane == 0) ws[WS_GX + v * 1536 + r] = d + b;
  }
}

// fence-free grid barrier: all communicated data uses device-scope atomics (L2-bypassing),
// so no L2 writeback/invalidate is needed -> enc/w_out stay cache-resident across steps.
static __device__ __forceinline__ void gridbar(int* bars, int t) {
  __syncthreads();  // per-wave vmcnt drain: all prior atomics reached the coherence point
  int* cbase = bars + t * 128;
  int* epoch = bars + MAXLEN * 128;
  if (threadIdx.x == 0)
    __hip_atomic_fetch_add(cbase + (blockIdx.x & (NGRP - 1)) * 4, 1,
                           __ATOMIC_RELEASE, __HIP_MEMORY_SCOPE_AGENT);
  if (blockIdx.x == 0) {
    if (threadIdx.x < 64) {  // wave-parallel scan of all 32 counters
      for (;;) {
        int c = AL(cbase + (threadIdx.x & 31) * 4);
        if (__all(c >= GRPSZ)) break;
        __builtin_amdgcn_s_sleep(1);
      }
      if (threadIdx.x < 8)
        __hip_atomic_store(epoch + threadIdx.x * 4, t + 1,
                           __ATOMIC_RELEASE, __HIP_MEMORY_SCOPE_AGENT);
    }
  } else {
    if (threadIdx.x == 0) {
      while (AL(epoch + (blockIdx.x & 7) * 4) < t + 1)
        __builtin_amdgcn_s_sleep(4);
    }
  }
  __syncthreads();
}

__global__ __launch_bounds__(TPB) void k_persist(const float* __restrict__ enc,
                                                 const float* __restrict__ w_hh,
                                                 const float* __restrict__ b_hh,
                                                 const float* __restrict__ w_out,
                                                 const float* __restrict__ b_out,
                                                 float* __restrict__ ws,
                                                 float* __restrict__ dout) {
  const int tid = threadIdx.x, blk = blockIdx.x;
  const int w = tid >> 6, lane = tid & 63;
  __shared__ __align__(16) float h2[2][HID];
  __shared__ __align__(16) float uld[HID];
  __shared__ __align__(16) float whh_lds[6][HID];
  __shared__ float sblk[KPB];      // e^{s_i} for this block's 64 keys (persists across barrier)
  __shared__ float pb_lds[32];     // w_out_h . h_new + b_out (persists across barrier)
  __shared__ float lgs[34];        // [0..30] logits, [32] T1tot
  __shared__ float ered[8];
  int best = EOSI, len = MAXLEN;
  int* bars = (int*)ws + WS_BAR;

  for (int i = tid; i < 6 * HID; i += TPB)
    whh_lds[i >> 9][i & 511] = w_hh[(size_t)blk * (6 * HID) + i];
  if (tid < HID) h2[0][tid] = 0.f;
  __syncthreads();

#pragma unroll 1
  for (int t = 0;; ++t) {
    float* h = h2[t & 1];
    float* hn = h2[(t + 1) & 1];

    // ================= phase A: finalize step t-1 =================
    if (t > 0) {
      const float* LT = ws + WS_LT + ((t - 1) % 3) * 272;
      if (tid < 64) {
        float val = 0.f;
        if (lane < VOCAB) {
#pragma unroll
          for (int s = 0; s < 8; ++s) val += AL(LT + s * 32 + lane);
        } else if (lane == 32) {
#pragma unroll
          for (int s = 0; s < 8; ++s) val += AL(LT + 256 + s);
        }
        float t1 = __shfl(val, 32, 64);
        if (lane < VOCAB) lgs[lane] = val / t1 + pb_lds[lane];
        if (lane == 32) lgs[32] = t1;
      }
      __syncthreads();
      float bv = lgs[0];
      int bb = 0;
#pragma unroll
      for (int v = 1; v < VOCAB; ++v) {
        float x = lgs[v];
        if (x > bv) { bv = x; bb = v; }
      }
      best = bb;
      if (bb == EOSI && len == MAXLEN) len = t - 1;
      float invT1 = 1.0f / lgs[32];
      if (tid < KPB)
        dout[OUT_ATT_BASE + (size_t)(t - 1) * TENC + blk * KPB + tid] = sblk[tid] * invT1;
      if (blk == 0) {
        if (tid < VOCAB) dout[(size_t)(t - 1) * VOCAB + tid] = lgs[tid];
        if (t == MAXLEN && tid == 0) dout[OUT_LEN_IDX] = (float)len;
        float* LTn = ws + WS_LT + ((t + 1) % 3) * 272;
        if (tid < 264) AS(LTn + tid, 0.0f);  // zero buffer for step t+1
      }
    }
    if (t == MAXLEN) break;

    // ================= phase B =================
    // B1: GRU (redundant per block, bitwise identical)
    {
      const float* gx = ws + WS_GX + best * 1536;
      const float* ghb = ws + WS_GH + (t & 1) * 1536;
      float gxr = gx[tid], gxz = gx[HID + tid], gxn = gx[2 * HID + tid];
      float ghr = AL(ghb + tid), ghz = AL(ghb + HID + tid), ghn = AL(ghb + 2 * HID + tid);
      float rg = sigm(gxr + ghr);
      float zg = sigm(gxz + ghz);
      float ng = tanhf(gxn + rg * ghn);
      hn[tid] = (1.f - zg) * ng + zg * h[tid];
      uld[tid] = 0.f;
    }
    __syncthreads();

    // B2: gh(t+1) slice, rows blk*6 .. +5 (LDS weights x LDS hn)
    if (w < 6) {
      const float* wr = whh_lds[w];
      float4 w0 = *(const float4*)(wr + lane * 8);
      float4 w1 = *(const float4*)(wr + lane * 8 + 4);
      float4 hv0 = *(const float4*)(&hn[lane * 8]);
      float4 hv1 = *(const float4*)(&hn[lane * 8 + 4]);
      float acc = w0.x*hv0.x + w0.y*hv0.y + w0.z*hv0.z + w0.w*hv0.w
                + w1.x*hv1.x + w1.y*hv1.y + w1.z*hv1.z + w1.w*hv1.w;
      acc = wsum(acc);
      if (lane == 0) {
        int r = blk * 6 + w;
        AS(ws + WS_GH + ((t + 1) & 1) * 1536 + r, acc + b_hh[r]);
      }
    }

    // B3+B4: scores + PV in one pass over this block's 64 enc rows (wave w: rows w*8..w*8+7)
    float hr[8];
#pragma unroll
    for (int j = 0; j < 8; ++j) hr[j] = hn[lane * 8 + j];
    float ps[8] = {0, 0, 0, 0, 0, 0, 0, 0};
    float esum = 0.f;
#pragma unroll 2
    for (int rr = 0; rr < 8; ++rr) {
      int row = blk * KPB + w * 8 + rr;
      const float* rp = enc + (size_t)row * 1024 + lane * 8;
      float4 k0 = *(const float4*)(rp);
      float4 k1 = *(const float4*)(rp + 4);
      float4 v0 = *(const float4*)(rp + 512);
      float4 v1 = *(const float4*)(rp + 516);
      float d = hr[0]*k0.x + hr[1]*k0.y + hr[2]*k0.z + hr[3]*k0.w
              + hr[4]*k1.x + hr[5]*k1.y + hr[6]*k1.z + hr[7]*k1.w;
      bool okl = (k0.x != 30.f) || (k0.y != 30.f) || (k0.z != 30.f) || (k0.w != 30.f)
               || (k1.x != 30.f) || (k1.y != 30.f) || (k1.z != 30.f) || (k1.w != 30.f);
      float s = wsum(d);
      bool ok = (__ballot(okl) != 0ull);
      float e = ok ? expf(s * SCALE) : 0.0f;   // no-max softmax: |s*SCALE| <= ~23, e^s fits fp32
      if (lane == 0) sblk[w * 8 + rr] = e;
      esum += e;
      ps[0] += e * v0.x; ps[1] += e * v0.y; ps[2] += e * v0.z; ps[3] += e * v0.w;
      ps[4] += e * v1.x; ps[5] += e * v1.y; ps[6] += e * v1.z; ps[7] += e * v1.w;
    }
    if (lane == 0) ered[w] = esum;
#pragma unroll
    for (int j = 0; j < 8; ++j) atomicAdd(&uld[lane * 8 + j], ps[j]);
    __syncthreads();
    if (tid == 0) {
      float T1p = ered[0] + ered[1] + ered[2] + ered[3]
                + ered[4] + ered[5] + ered[6] + ered[7];
      atomicAdd(ws + WS_LT + (t % 3) * 272 + 256 + (blk & 7), T1p);
    }

    // B5: logit partials. pl = w_out_s . u_blk (atomic-summed); pb = w_out_h . hn (redundant)
    for (int r = w; r < VOCAB; r += 8) {
      const float* wo = w_out + (size_t)r * 1024 + lane * 8;
      float4 a0 = *(const float4*)(wo);
      float4 a1 = *(const float4*)(wo + 4);
      float4 b0 = *(const float4*)(wo + 512);
      float4 b1 = *(const float4*)(wo + 516);
      float4 u0 = *(const float4*)(&uld[lane * 8]);
      float4 u1 = *(const float4*)(&uld[lane * 8 + 4]);
      float4 q0 = *(const float4*)(&hn[lane * 8]);
      float4 q1 = *(const float4*)(&hn[lane * 8 + 4]);
      float accs = a0.x*u0.x + a0.y*u0.y + a0.z*u0.z + a0.w*u0.w
                 + a1.x*u1.x + a1.y*u1.y + a1.z*u1.z + a1.w*u1.w;
      float acch = b0.x*q0.x + b0.y*q0.y + b0.z*q0.z + b0.w*q0.w
                 + b1.x*q1.x + b1.y*q1.y + b1.z*q1.z + b1.w*q1.w;
      accs = wsum(accs);
      acch = wsum(acch);
      if (lane == 0) {
        atomicAdd(ws + WS_LT + (t % 3) * 272 + (blk & 7) * 32 + r, accs);
        pb_lds[r] = acch + b_out[r];
      }
    }

    gridbar(bars, t);
  }
}

extern "C" void kernel_launch(void* const* d_in, const int* in_sizes, int n_in,
                              void* d_out, int out_size, void* d_ws, size_t ws_size,
                              hipStream_t stream) {
  const float* enc   = (const float*)d_in[0];
  const float* embed = (const float*)d_in[2];
  const float* w_ih  = (const float*)d_in[3];
  const float* w_hh  = (const float*)d_in[4];
  const float* b_ih  = (const float*)d_in[5];
  const float* b_hh  = (const float*)d_in[6];
  const float* w_out = (const float*)d_in[7];
  const float* b_out = (const float*)d_in[8];
  float* dout = (float*)d_out;
  float* ws = (float*)d_ws;

  hipLaunchKernelGGL(k_init, dim3(13), dim3(1024), 0, stream, b_hh, ws);
  hipLaunchKernelGGL(k_gx_all, dim3(384), dim3(256), 0, stream, embed, w_ih, b_ih, ws);
  hipLaunchKernelGGL(k_persist, dim3(NBLK), dim3(TPB), 0, stream,
                     enc, w_hh, b_hh, w_out, b_out, ws, dout);
}

// Round 7
// 2764.240 us; speedup vs baseline: 5.5618x; 1.2828x over previous
//
#include <hip/hip_runtime.h>
#include <math.h>

#define HID 512
#define TENC 16384
#define NBLK 256
#define TPB 512
#define KPB 64
#define NGRP 32
#define GRPSZ 8
#define VOCAB 31
#define EOSI 29
#define MAXLEN 100
#define SCALE 0.044194173824159216f

// ws layout (4-byte units)
#define WS_GX    0          // 31*1536 = 47616
#define WS_GH    47616      // 2*1536 (double buffer)
#define WS_LT    50688      // 3 buffers * 272  (8 slots*32 lognum, +256: 8 T1)
#define WS_BAR   51504      // ints: 100*128 counters + 8*4 epoch = 12832

#define OUT_LEN_IDX 3100
#define OUT_ATT_BASE 3101

#define AL(p)    __hip_atomic_load((p), __ATOMIC_RELAXED, __HIP_MEMORY_SCOPE_AGENT)
#define AS(p, v) __hip_atomic_store((p), (v), __ATOMIC_RELAXED, __HIP_MEMORY_SCOPE_AGENT)

static __device__ __forceinline__ float wsum(float v) {
#pragma unroll
  for (int m = 32; m >= 1; m >>= 1) v += __shfl_xor(v, m, 64);
  return v;
}
static __device__ __forceinline__ float sigm(float x) { return 1.0f / (1.0f + expf(-x)); }

__global__ __launch_bounds__(1024) void k_init(const float* __restrict__ b_hh,
                                               float* __restrict__ ws) {
  int idx = blockIdx.x * 1024 + threadIdx.x;
  int* bars = (int*)ws + WS_BAR;
  if (idx < 12832) bars[idx] = 0;
  if (idx < 1536) ws[WS_GH + idx] = b_hh[idx];  // gh(0) = W_hh*0 + b_hh (buffer 0)
  if (idx < 816) ws[WS_LT + idx] = 0.0f;        // all 3 LT buffers
}

__global__ __launch_bounds__(256) void k_gx_all(const float* __restrict__ embed,
                                                const float* __restrict__ w_ih,
                                                const float* __restrict__ b_ih,
                                                float* __restrict__ ws) {
  int w = threadIdx.x >> 6, lane = threadIdx.x & 63;
  int r = blockIdx.x * 4 + w;
  float wr[8];
  const float* wp = w_ih + (size_t)r * HID + lane * 8;
#pragma unroll
  for (int j = 0; j < 8; ++j) wr[j] = wp[j];
  float b = b_ih[r];
  for (int v = 0; v < VOCAB; ++v) {
    const float* e = embed + (size_t)v * HID + lane * 8;
    float d = 0.f;
#pragma unroll
    for (int j = 0; j < 8; ++j) d += wr[j] * e[j];
    d = wsum(d);
    if (lane == 0) ws[WS_GX + v * 1536 + r] = d + b;
  }
}

// fence-free grid barrier: all cross-block data moves via device-scope atomics
// (coherence-point ops), so no L2 writeback/invalidate -> caches stay warm.
static __device__ __forceinline__ void gridbar(int* bars, int t) {
  __syncthreads();
  int* cbase = bars + t * 128;
  int* epoch = bars + MAXLEN * 128;
  if (threadIdx.x == 0)
    __hip_atomic_fetch_add(cbase + (blockIdx.x & (NGRP - 1)) * 4, 1,
                           __ATOMIC_RELEASE, __HIP_MEMORY_SCOPE_AGENT);
  if (blockIdx.x == 0) {
    if (threadIdx.x < 64) {  // wave-parallel scan of all 32 counters
      for (;;) {
        int c = AL(cbase + (threadIdx.x & 31) * 4);
        if (__all(c >= GRPSZ)) break;
        __builtin_amdgcn_s_sleep(1);
      }
      if (threadIdx.x < 8)
        __hip_atomic_store(epoch + threadIdx.x * 4, t + 1,
                           __ATOMIC_RELEASE, __HIP_MEMORY_SCOPE_AGENT);
    }
  } else {
    if (threadIdx.x == 0) {
      while (AL(epoch + (blockIdx.x & 7) * 4) < t + 1)
        __builtin_amdgcn_s_sleep(4);
    }
  }
  __syncthreads();
}

__global__ __launch_bounds__(TPB, 1) void k_persist(const float* __restrict__ enc,
                                                    const float* __restrict__ w_hh,
                                                    const float* __restrict__ b_hh,
                                                    const float* __restrict__ w_out,
                                                    const float* __restrict__ b_out,
                                                    float* __restrict__ ws,
                                                    float* __restrict__ dout) {
  const int tid = threadIdx.x, blk = blockIdx.x;
  const int w = tid >> 6, lane = tid & 63;
  __shared__ __align__(16) float k_lds[KPB][HID];   // 128 KiB: this block's K rows
  __shared__ __align__(16) float h2[2][HID];
  __shared__ __align__(16) float uld[HID];
  __shared__ float sblk[KPB];      // e^{s_i} (persists across barrier)
  __shared__ float okf[KPB];       // PAD mask (1.0/0.0), h-independent
  __shared__ float pb_lds[32];     // w_out_h . h_new + b_out
  __shared__ float lgs[34];        // [0..30] logits, [32] T1tot
  __shared__ float ered[8];
  int best = EOSI, len = MAXLEN;
  int* bars = (int*)ws + WS_BAR;

  // ---- stage K into LDS + precompute mask (once) ----
#pragma unroll
  for (int rr = 0; rr < 8; ++rr) {
    int r = w * 8 + rr;
    const float* rp = enc + (size_t)(blk * KPB + r) * 1024 + lane * 8;
    float4 k0 = *(const float4*)(rp);
    float4 k1 = *(const float4*)(rp + 4);
    *(float4*)&k_lds[r][lane * 8] = k0;
    *(float4*)&k_lds[r][lane * 8 + 4] = k1;
    bool okl = (k0.x != 30.f) || (k0.y != 30.f) || (k0.z != 30.f) || (k0.w != 30.f)
             || (k1.x != 30.f) || (k1.y != 30.f) || (k1.z != 30.f) || (k1.w != 30.f);
    bool ok = (__ballot(okl) != 0ull);
    if (lane == 0) okf[r] = ok ? 1.0f : 0.0f;
  }
  if (tid < HID) h2[0][tid] = 0.f;
  __syncthreads();

#pragma unroll 1
  for (int t = 0;; ++t) {
    float* h = h2[t & 1];
    float* hn = h2[(t + 1) & 1];

    // ================= phase A: finalize step t-1 =================
    if (t > 0) {
      const float* LT = ws + WS_LT + ((t - 1) % 3) * 272;
      if (tid < 64) {
        float val = 0.f;
        if (lane < VOCAB) {
#pragma unroll
          for (int s = 0; s < 8; ++s) val += AL(LT + s * 32 + lane);
        } else if (lane == 32) {
#pragma unroll
          for (int s = 0; s < 8; ++s) val += AL(LT + 256 + s);
        }
        float t1 = __shfl(val, 32, 64);
        if (lane < VOCAB) lgs[lane] = val / t1 + pb_lds[lane];
        if (lane == 32) lgs[32] = t1;
      }
      __syncthreads();
      float bv = lgs[0];
      int bb = 0;
#pragma unroll
      for (int v = 1; v < VOCAB; ++v) {
        float x = lgs[v];
        if (x > bv) { bv = x; bb = v; }
      }
      best = bb;
      if (bb == EOSI && len == MAXLEN) len = t - 1;
      float invT1 = 1.0f / lgs[32];
      if (tid < KPB)
        dout[OUT_ATT_BASE + (size_t)(t - 1) * TENC + blk * KPB + tid] = sblk[tid] * invT1;
      if (blk == 0) {
        if (tid < VOCAB) dout[(size_t)(t - 1) * VOCAB + tid] = lgs[tid];
        if (t == MAXLEN && tid == 0) dout[OUT_LEN_IDX] = (float)len;
        float* LTn = ws + WS_LT + ((t + 1) % 3) * 272;
        if (tid < 264) AS(LTn + tid, 0.0f);  // zero buffer for step t+1
      }
    }
    if (t == MAXLEN) break;

    // ================= phase B =================
    // B1: GRU (redundant per block, bitwise identical)
    {
      const float* gx = ws + WS_GX + best * 1536;
      const float* ghb = ws + WS_GH + (t & 1) * 1536;
      float gxr = gx[tid], gxz = gx[HID + tid], gxn = gx[2 * HID + tid];
      float ghr = AL(ghb + tid), ghz = AL(ghb + HID + tid), ghn = AL(ghb + 2 * HID + tid);
      float rg = sigm(gxr + ghr);
      float zg = sigm(gxz + ghz);
      float ng = tanhf(gxn + rg * ghn);
      hn[tid] = (1.f - zg) * ng + zg * h[tid];
      uld[tid] = 0.f;
    }
    __syncthreads();

    // B2: gh(t+1) slice, rows blk*6 .. +5 (global w_hh, L2-hot, x LDS hn)
    if (w < 6) {
      int r = blk * 6 + w;
      const float* wp = w_hh + (size_t)r * HID + lane * 8;
      float4 w0 = *(const float4*)(wp);
      float4 w1 = *(const float4*)(wp + 4);
      float4 hv0 = *(const float4*)(&hn[lane * 8]);
      float4 hv1 = *(const float4*)(&hn[lane * 8 + 4]);
      float acc = w0.x*hv0.x + w0.y*hv0.y + w0.z*hv0.z + w0.w*hv0.w
                + w1.x*hv1.x + w1.y*hv1.y + w1.z*hv1.z + w1.w*hv1.w;
      acc = wsum(acc);
      if (lane == 0) AS(ws + WS_GH + ((t + 1) & 1) * 1536 + r, acc + b_hh[r]);
    }

    // B3: V loads issued first (16 outstanding 16B loads/wave), then K-dots from LDS
    float hr[8];
#pragma unroll
    for (int j = 0; j < 8; ++j) hr[j] = hn[lane * 8 + j];
    float4 v0[8], v1[8];
#pragma unroll
    for (int rr = 0; rr < 8; ++rr) {
      int row = blk * KPB + w * 8 + rr;
      const float* rp = enc + (size_t)row * 1024 + 512 + lane * 8;
      v0[rr] = *(const float4*)(rp);
      v1[rr] = *(const float4*)(rp + 4);
    }
    float ee[8];
    float esum = 0.f;
#pragma unroll
    for (int rr = 0; rr < 8; ++rr) {
      int r = w * 8 + rr;
      float4 k0 = *(const float4*)(&k_lds[r][lane * 8]);
      float4 k1 = *(const float4*)(&k_lds[r][lane * 8 + 4]);
      float d = hr[0]*k0.x + hr[1]*k0.y + hr[2]*k0.z + hr[3]*k0.w
              + hr[4]*k1.x + hr[5]*k1.y + hr[6]*k1.z + hr[7]*k1.w;
      float s = wsum(d);
      float e = okf[r] * __expf(s * SCALE);  // no-max softmax: |s*SCALE| <= ~23
      ee[rr] = e;
      if (lane == 0) sblk[r] = e;
      esum += e;
    }
    if (lane == 0) ered[w] = esum;
    {
      float ps[8] = {0, 0, 0, 0, 0, 0, 0, 0};
#pragma unroll
      for (int rr = 0; rr < 8; ++rr) {
        float e = ee[rr];
        ps[0] += e * v0[rr].x; ps[1] += e * v0[rr].y; ps[2] += e * v0[rr].z; ps[3] += e * v0[rr].w;
        ps[4] += e * v1[rr].x; ps[5] += e * v1[rr].y; ps[6] += e * v1[rr].z; ps[7] += e * v1[rr].w;
      }
#pragma unroll
      for (int j = 0; j < 8; ++j) atomicAdd(&uld[lane * 8 + j], ps[j]);
    }
    __syncthreads();
    if (tid == 0) {
      float T1p = ered[0] + ered[1] + ered[2] + ered[3]
                + ered[4] + ered[5] + ered[6] + ered[7];
      atomicAdd(ws + WS_LT + (t % 3) * 272 + 256 + (blk & 7), T1p);
    }

    // B5: logit partials. accs = w_out_s . u_blk (atomic-summed); acch redundant
    for (int r = w; r < VOCAB; r += 8) {
      const float* wo = w_out + (size_t)r * 1024 + lane * 8;
      float4 a0 = *(const float4*)(wo);
      float4 a1 = *(const float4*)(wo + 4);
      float4 b0 = *(const float4*)(wo + 512);
      float4 b1 = *(const float4*)(wo + 516);
      float4 u0 = *(const float4*)(&uld[lane * 8]);
      float4 u1 = *(const float4*)(&uld[lane * 8 + 4]);
      float4 q0 = *(const float4*)(&hn[lane * 8]);
      float4 q1 = *(const float4*)(&hn[lane * 8 + 4]);
      float accs = a0.x*u0.x + a0.y*u0.y + a0.z*u0.z + a0.w*u0.w
                 + a1.x*u1.x + a1.y*u1.y + a1.z*u1.z + a1.w*u1.w;
      float acch = b0.x*q0.x + b0.y*q0.y + b0.z*q0.z + b0.w*q0.w
                 + b1.x*q1.x + b1.y*q1.y + b1.z*q1.z + b1.w*q1.w;
      accs = wsum(accs);
      acch = wsum(acch);
      if (lane == 0) {
        atomicAdd(ws + WS_LT + (t % 3) * 272 + (blk & 7) * 32 + r, accs);
        pb_lds[r] = acch + b_out[r];
      }
    }

    gridbar(bars, t);
  }
}

extern "C" void kernel_launch(void* const* d_in, const int* in_sizes, int n_in,
                              void* d_out, int out_size, void* d_ws, size_t ws_size,
                              hipStream_t stream) {
  const float* enc   = (const float*)d_in[0];
  const float* embed = (const float*)d_in[2];
  const float* w_ih  = (const float*)d_in[3];
  const float* w_hh  = (const float*)d_in[4];
  const float* b_ih  = (const float*)d_in[5];
  const float* b_hh  = (const float*)d_in[6];
  const float* w_out = (const float*)d_in[7];
  const float* b_out = (const float*)d_in[8];
  float* dout = (float*)d_out;
  float* ws = (float*)d_ws;

  hipLaunchKernelGGL(k_init, dim3(13), dim3(1024), 0, stream, b_hh, ws);
  hipLaunchKernelGGL(k_gx_all, dim3(384), dim3(256), 0, stream, embed, w_ih, b_ih, ws);
  hipLaunchKernelGGL(k_persist, dim3(NBLK), dim3(TPB), 0, stream,
                     enc, w_hh, b_hh, w_out, b_out, ws, dout);
}

// Round 8
// 2279.700 us; speedup vs baseline: 6.7439x; 1.2125x over previous
//
#include <hip/hip_runtime.h>
#include <math.h>

#define HID 512
#define TENC 16384
#define NBLK 256
#define TPB 512
#define KPB 64
#define NGRP 32
#define GRPSZ 8
#define VOCAB 31
#define EOSI 29
#define MAXLEN 100
#define SCALE 0.044194173824159216f

// ws layout (4-byte units)
#define WS_GX    0          // 31*1536 = 47616
#define WS_GH    47616      // 2*1536 (double buffer)
#define WS_LT    50688      // 3 buffers * 272  (8 slots*32 lognum, +256: 8 T1)
#define WS_BAR   51504      // ints: 100*128 counters + 32*4 epoch = 12928

#define OUT_LEN_IDX 3100
#define OUT_ATT_BASE 3101

#define AL(p)    __hip_atomic_load((p), __ATOMIC_RELAXED, __HIP_MEMORY_SCOPE_AGENT)
#define AS(p, v) __hip_atomic_store((p), (v), __ATOMIC_RELAXED, __HIP_MEMORY_SCOPE_AGENT)

static __device__ __forceinline__ float wsum(float v) {
#pragma unroll
  for (int m = 32; m >= 1; m >>= 1) v += __shfl_xor(v, m, 64);
  return v;
}
static __device__ __forceinline__ float sigm(float x) { return 1.0f / (1.0f + __expf(-x)); }
static __device__ __forceinline__ float ftanh(float x) {
  return 1.0f - 2.0f / (__expf(2.0f * x) + 1.0f);
}

__global__ __launch_bounds__(1024) void k_init(const float* __restrict__ b_hh,
                                               float* __restrict__ ws) {
  int idx = blockIdx.x * 1024 + threadIdx.x;
  int* bars = (int*)ws + WS_BAR;
  if (idx < 12928) bars[idx] = 0;
  if (idx < 1536) ws[WS_GH + idx] = b_hh[idx];  // gh(0) = W_hh*0 + b_hh (buffer 0)
  if (idx < 816) ws[WS_LT + idx] = 0.0f;        // all 3 LT buffers
}

__global__ __launch_bounds__(256) void k_gx_all(const float* __restrict__ embed,
                                                const float* __restrict__ w_ih,
                                                const float* __restrict__ b_ih,
                                                float* __restrict__ ws) {
  int w = threadIdx.x >> 6, lane = threadIdx.x & 63;
  int r = blockIdx.x * 4 + w;
  float wr[8];
  const float* wp = w_ih + (size_t)r * HID + lane * 8;
#pragma unroll
  for (int j = 0; j < 8; ++j) wr[j] = wp[j];
  float b = b_ih[r];
  for (int v = 0; v < VOCAB; ++v) {
    const float* e = embed + (size_t)v * HID + lane * 8;
    float d = 0.f;
#pragma unroll
    for (int j = 0; j < 8; ++j) d += wr[j] * e[j];
    d = wsum(d);
    if (lane == 0) ws[WS_GX + v * 1536 + r] = d + b;
  }
}

// fence-free grid barrier: cross-block data moves via device-scope atomics only,
// so no L2 writeback/invalidate -> caches stay warm. Epoch replicated x32.
static __device__ __forceinline__ void gridbar(int* bars, int t) {
  __syncthreads();
  int* cbase = bars + t * 128;
  int* epoch = bars + MAXLEN * 128;  // 32 lines x 16B
  if (threadIdx.x == 0)
    __hip_atomic_fetch_add(cbase + (blockIdx.x & 31) * 4, 1,
                           __ATOMIC_RELEASE, __HIP_MEMORY_SCOPE_AGENT);
  if (blockIdx.x == 0) {
    if (threadIdx.x < 32) {
      for (;;) {
        int c = AL(cbase + threadIdx.x * 4);
        if (__all(c >= GRPSZ)) break;
        __builtin_amdgcn_s_sleep(1);
      }
      __hip_atomic_store(epoch + threadIdx.x * 4, t + 1,
                         __ATOMIC_RELEASE, __HIP_MEMORY_SCOPE_AGENT);
    }
  } else {
    if (threadIdx.x == 0) {
      while (AL(epoch + (blockIdx.x & 31) * 4) < t + 1)
        __builtin_amdgcn_s_sleep(2);
    }
  }
  __syncthreads();
}

__global__ __launch_bounds__(TPB, 1) void k_persist(const float* __restrict__ enc,
                                                    const float* __restrict__ w_hh,
                                                    const float* __restrict__ b_hh,
                                                    const float* __restrict__ w_out,
                                                    const float* __restrict__ b_out,
                                                    float* __restrict__ ws,
                                                    float* __restrict__ dout) {
  const int tid = threadIdx.x, blk = blockIdx.x;
  const int w = tid >> 6, lane = tid & 63;
  __shared__ __align__(16) float k_lds[KPB][HID];   // 128 KiB
  __shared__ __align__(16) float uwave[8][HID];     // 16 KiB per-wave PV partials
  __shared__ __align__(16) float h2[2][HID];
  __shared__ __align__(16) float uld[HID];
  __shared__ float sblk[KPB];
  __shared__ float okf[KPB];
  __shared__ float pb_lds[32];
  __shared__ float lgs[34];
  __shared__ float ered[8];
  int best = EOSI, len = MAXLEN;
  int* bars = (int*)ws + WS_BAR;

  // ---- stage K into LDS (lane*4 / 256+lane*4 mapping, bank-perfect), V into REGISTERS ----
  float4 v0[8], v1[8];
#pragma unroll
  for (int rr = 0; rr < 8; ++rr) {
    int r = w * 8 + rr;
    const float* rp = enc + (size_t)(blk * KPB + r) * 1024;
    float4 k0 = *(const float4*)(rp + lane * 4);
    float4 k1 = *(const float4*)(rp + 256 + lane * 4);
    v0[rr] = *(const float4*)(rp + 512 + lane * 4);
    v1[rr] = *(const float4*)(rp + 768 + lane * 4);
    *(float4*)&k_lds[r][lane * 4] = k0;
    *(float4*)&k_lds[r][256 + lane * 4] = k1;
    bool okl = (k0.x != 30.f) || (k0.y != 30.f) || (k0.z != 30.f) || (k0.w != 30.f)
             || (k1.x != 30.f) || (k1.y != 30.f) || (k1.z != 30.f) || (k1.w != 30.f);
    bool ok = (__ballot(okl) != 0ull);
    if (lane == 0) okf[r] = ok ? 1.0f : 0.0f;
  }
  if (tid < HID) h2[0][tid] = 0.f;
  __syncthreads();

#pragma unroll 1
  for (int t = 0;; ++t) {
    float* h = h2[t & 1];
    float* hn = h2[(t + 1) & 1];

    // ================= phase A: finalize step t-1 =================
    if (t > 0) {
      const float* LT = ws + WS_LT + ((t - 1) % 3) * 272;
      if (tid < 64) {
        float val = 0.f;
        if (lane < VOCAB) {
#pragma unroll
          for (int s = 0; s < 8; ++s) val += AL(LT + s * 32 + lane);
        } else if (lane == 32) {
#pragma unroll
          for (int s = 0; s < 8; ++s) val += AL(LT + 256 + s);
        }
        float t1 = __shfl(val, 32, 64);
        if (lane < VOCAB) lgs[lane] = val / t1 + pb_lds[lane];
        if (lane == 32) lgs[32] = t1;
      }
      __syncthreads();
      float bv = lgs[0];
      int bb = 0;
#pragma unroll
      for (int v = 1; v < VOCAB; ++v) {
        float x = lgs[v];
        if (x > bv) { bv = x; bb = v; }
      }
      best = bb;
      if (bb == EOSI && len == MAXLEN) len = t - 1;
      float invT1 = 1.0f / lgs[32];
      if (tid < KPB)
        dout[OUT_ATT_BASE + (size_t)(t - 1) * TENC + blk * KPB + tid] = sblk[tid] * invT1;
      if (blk == 17) {
        if (tid < VOCAB) dout[(size_t)(t - 1) * VOCAB + tid] = lgs[tid];
        if (t == MAXLEN && tid == 0) dout[OUT_LEN_IDX] = (float)len;
      }
      if (blk == 9) {
        float* LTn = ws + WS_LT + ((t + 1) % 3) * 272;
        if (tid < 264) AS(LTn + tid, 0.0f);  // zero buffer for step t+1
      }
    }
    if (t == MAXLEN) break;

    // ================= phase B =================
    // B1: GRU (redundant per block, bitwise identical)
    {
      const float* gx = ws + WS_GX + best * 1536;
      const float* ghb = ws + WS_GH + (t & 1) * 1536;
      float gxr = gx[tid], gxz = gx[HID + tid], gxn = gx[2 * HID + tid];
      float ghr = AL(ghb + tid), ghz = AL(ghb + HID + tid), ghn = AL(ghb + 2 * HID + tid);
      float rg = sigm(gxr + ghr);
      float zg = sigm(gxz + ghz);
      float ng = ftanh(gxn + rg * ghn);
      hn[tid] = (1.f - zg) * ng + zg * h[tid];
    }
    __syncthreads();

    // B2: gh(t+1) slice, rows blk*6 .. +5 (global w_hh, L2-hot, x LDS hn)
    if (w < 6) {
      int r = blk * 6 + w;
      const float* wp = w_hh + (size_t)r * HID;
      float4 w0 = *(const float4*)(wp + lane * 4);
      float4 w1 = *(const float4*)(wp + 256 + lane * 4);
      float4 hv0 = *(const float4*)(&hn[lane * 4]);
      float4 hv1 = *(const float4*)(&hn[256 + lane * 4]);
      float acc = w0.x*hv0.x + w0.y*hv0.y + w0.z*hv0.z + w0.w*hv0.w
                + w1.x*hv1.x + w1.y*hv1.y + w1.z*hv1.z + w1.w*hv1.w;
      acc = wsum(acc);
      if (lane == 0) AS(ws + WS_GH + ((t + 1) & 1) * 1536 + r, acc + b_hh[r]);
    }

    // B3: scores from LDS K (bank-perfect), V from registers
    float4 hv0 = *(const float4*)(&hn[lane * 4]);
    float4 hv1 = *(const float4*)(&hn[256 + lane * 4]);
    float ee[8];
    float esum = 0.f;
#pragma unroll
    for (int rr = 0; rr < 8; ++rr) {
      int r = w * 8 + rr;
      float4 k0 = *(const float4*)(&k_lds[r][lane * 4]);
      float4 k1 = *(const float4*)(&k_lds[r][256 + lane * 4]);
      float d = hv0.x*k0.x + hv0.y*k0.y + hv0.z*k0.z + hv0.w*k0.w
              + hv1.x*k1.x + hv1.y*k1.y + hv1.z*k1.z + hv1.w*k1.w;
      float s = wsum(d);
      float e = okf[r] * __expf(s * SCALE);  // no-max softmax: |s*SCALE| <= ~23
      ee[rr] = e;
      if (lane == 0) sblk[r] = e;
      esum += e;
    }
    if (lane == 0) ered[w] = esum;
    {
      float p0 = 0.f, p1 = 0.f, p2 = 0.f, p3 = 0.f;
      float p4 = 0.f, p5 = 0.f, p6 = 0.f, p7 = 0.f;
#pragma unroll
      for (int rr = 0; rr < 8; ++rr) {
        float e = ee[rr];
        p0 += e * v0[rr].x; p1 += e * v0[rr].y; p2 += e * v0[rr].z; p3 += e * v0[rr].w;
        p4 += e * v1[rr].x; p5 += e * v1[rr].y; p6 += e * v1[rr].z; p7 += e * v1[rr].w;
      }
      *(float4*)&uwave[w][lane * 4] = make_float4(p0, p1, p2, p3);
      *(float4*)&uwave[w][256 + lane * 4] = make_float4(p4, p5, p6, p7);
    }
    __syncthreads();
    // cross-wave reduce of PV partials (stride-512 reads, conflict-free)
    {
      float a = uwave[0][tid] + uwave[1][tid] + uwave[2][tid] + uwave[3][tid]
              + uwave[4][tid] + uwave[5][tid] + uwave[6][tid] + uwave[7][tid];
      uld[tid] = a;
    }
    if (tid == 0) {
      float T1p = ered[0] + ered[1] + ered[2] + ered[3]
                + ered[4] + ered[5] + ered[6] + ered[7];
      atomicAdd(ws + WS_LT + (t % 3) * 272 + 256 + (blk & 7), T1p);
    }
    __syncthreads();

    // B5: logit partials. accs = w_out_s . u_blk (atomic-summed); acch redundant
    for (int r = w; r < VOCAB; r += 8) {
      const float* wo = w_out + (size_t)r * 1024;
      float4 a0 = *(const float4*)(wo + lane * 4);
      float4 a1 = *(const float4*)(wo + 256 + lane * 4);
      float4 b0 = *(const float4*)(wo + 512 + lane * 4);
      float4 b1 = *(const float4*)(wo + 768 + lane * 4);
      float4 u0 = *(const float4*)(&uld[lane * 4]);
      float4 u1 = *(const float4*)(&uld[256 + lane * 4]);
      float4 q0 = *(const float4*)(&hn[lane * 4]);
      float4 q1 = *(const float4*)(&hn[256 + lane * 4]);
      float accs = a0.x*u0.x + a0.y*u0.y + a0.z*u0.z + a0.w*u0.w
                 + a1.x*u1.x + a1.y*u1.y + a1.z*u1.z + a1.w*u1.w;
      float acch = b0.x*q0.x + b0.y*q0.y + b0.z*q0.z + b0.w*q0.w
                 + b1.x*q1.x + b1.y*q1.y + b1.z*q1.z + b1.w*q1.w;
      accs = wsum(accs);
      acch = wsum(acch);
      if (lane == 0) {
        atomicAdd(ws + WS_LT + (t % 3) * 272 + (blk & 7) * 32 + r, accs);
        pb_lds[r] = acch + b_out[r];
      }
    }

    gridbar(bars, t);
  }
}

extern "C" void kernel_launch(void* const* d_in, const int* in_sizes, int n_in,
                              void* d_out, int out_size, void* d_ws, size_t ws_size,
                              hipStream_t stream) {
  const float* enc   = (const float*)d_in[0];
  const float* embed = (const float*)d_in[2];
  const float* w_ih  = (const float*)d_in[3];
  const float* w_hh  = (const float*)d_in[4];
  const float* b_ih  = (const float*)d_in[5];
  const float* b_hh  = (const float*)d_in[6];
  const float* w_out = (const float*)d_in[7];
  const float* b_out = (const float*)d_in[8];
  float* dout = (float*)d_out;
  float* ws = (float*)d_ws;

  hipLaunchKernelGGL(k_init, dim3(13), dim3(1024), 0, stream, b_hh, ws);
  hipLaunchKernelGGL(k_gx_all, dim3(384), dim3(256), 0, stream, embed, w_ih, b_ih, ws);
  hipLaunchKernelGGL(k_persist, dim3(NBLK), dim3(TPB), 0, stream,
                     enc, w_hh, b_hh, w_out, b_out, ws, dout);
}